// Round 3
// baseline (141.959 us; speedup 1.0000x reference)
//
#include <hip/hip_runtime.h>
#include <hip/hip_fp16.h>

// Problem geometry (fixed by the reference)
constexpr int K    = 512;     // inner dim
constexpr int ROWS = 1024;    // B*T = 4*256
constexpr int COLS = 512;     // OUT
constexpr int NX   = ROWS * K;   // decoded x element count
constexpr int NW   = COLS * K;   // decoded w element count

// ---------------------------------------------------------------------------
// Kernel 1: decode pulse bits -> exact fp16 value (as fp32), stored in a
// k-pair-major packed layout for the GEMM:
//   xc2[k2][row][j]  (k2 = k>>1, j = k&1)   at dec[0 ..)
//   wc2[k2][col][j]                          at dec[NX ..)
// Reads: LDS-transpose so every global load is fully coalesced.
// ---------------------------------------------------------------------------
__global__ __launch_bounds__(256) void decode_k(const float* __restrict__ xp,
                                                const float* __restrict__ wp,
                                                float* __restrict__ dec) {
    __shared__ float lds[256 * 17];          // odd element stride: conflict-free
    const int t = threadIdx.x;
    const int ebase = blockIdx.x << 8;       // 256 elements per block
    const float4* s4 = (ebase < NX)
        ? (const float4*)(xp + (size_t)ebase * 16)
        : (const float4*)(wp + (size_t)(ebase - NX) * 16);

    #pragma unroll
    for (int j = 0; j < 4; ++j) {
        const int f = t + (j << 8);          // float4 index: 16 B lane stride
        const float4 v = s4[f];
        const int e = f >> 2;
        const int q = f & 3;
        *(float4*)&lds[e * 17 + (q << 2)] = v;
    }
    __syncthreads();

    const float* m = &lds[t * 17];
    unsigned u = 0;
    #pragma unroll
    for (int k = 0; k < 16; ++k)
        u |= ((__float_as_uint(m[k]) >> 23) & 1u) << k;   // 1.0f bit23
    const float val = __half2float(__ushort_as_half((unsigned short)u));

    const int e = ebase + t;
    size_t addr;
    if (e < NX) {                            // x: e = row*512 + k
        const int row = e >> 9, k = e & 511;
        addr = (size_t)(k >> 1) * (2 * ROWS) + row * 2 + (k & 1);
    } else {                                 // w: ew = col*512 + k
        const int ew = e - NX;
        const int col = ew >> 9, k = ew & 511;
        addr = (size_t)NX + (size_t)(k >> 1) * (2 * COLS) + col * 2 + (k & 1);
    }
    dec[addr] = val;                         // 3 MB total, L2-resident
}

// ---------------------------------------------------------------------------
// Kernel 2: GEMM, bit-exact sequential fp32 accumulation (ascending k),
// then fp16 RNE + pulse re-encode.
// No LDS, no SMEM, no barriers: pure VMEM (vmcnt, in-order) + FMA stream.
// Thread tile 2x2: one dwordx4 = {2 rows x 2 ks} of A, one = {2 cols x 2 ks}
// of B -> 8 FMAs per 2 loads. Block = 32x32 tile, grid (16,32) = 512 blocks
// -> 2 blocks/CU, 8 waves/CU.
// ---------------------------------------------------------------------------
__device__ __forceinline__ void store_bits(float* o, unsigned short u) {
    float4 q;
    q.x = (float)((u >> 0) & 1);  q.y = (float)((u >> 1) & 1);
    q.z = (float)((u >> 2) & 1);  q.w = (float)((u >> 3) & 1);
    *(float4*)(o + 0) = q;
    q.x = (float)((u >> 4) & 1);  q.y = (float)((u >> 5) & 1);
    q.z = (float)((u >> 6) & 1);  q.w = (float)((u >> 7) & 1);
    *(float4*)(o + 4) = q;
    q.x = (float)((u >> 8) & 1);  q.y = (float)((u >> 9) & 1);
    q.z = (float)((u >> 10) & 1); q.w = (float)((u >> 11) & 1);
    *(float4*)(o + 8) = q;
    q.x = (float)((u >> 12) & 1); q.y = (float)((u >> 13) & 1);
    q.z = (float)((u >> 14) & 1); q.w = (float)((u >> 15) & 1);
    *(float4*)(o + 12) = q;
}

__global__ __launch_bounds__(256, 2) void gemm_k(const float* __restrict__ dec,
                                                 float* __restrict__ out) {
    const float* __restrict__ xc = dec;        // [256][1024][2]
    const float* __restrict__ wc = dec + NX;   // [256][512][2]

    const int t  = threadIdx.x;
    const int tx = t & 15;                     // col-pair index in block
    const int ty = t >> 4;                     // row-pair index in block
    const int c  = (blockIdx.x << 5) + (tx << 1);
    const int r  = (blockIdx.y << 5) + (ty << 1);

    const float* ap = xc + r * 2;              // + k2*2048, 16B-aligned (r even)
    const float* bp = wc + c * 2;              // + k2*1024, 16B-aligned (c even)

    float acc00 = 0.f, acc01 = 0.f, acc10 = 0.f, acc11 = 0.f;

    #pragma unroll 8
    for (int k2 = 0; k2 < 256; ++k2) {
        const float4 A = *(const float4*)(ap + (size_t)k2 * (2 * ROWS));
        const float4 B = *(const float4*)(bp + (size_t)k2 * (2 * COLS));
        // A = {a[r][2k2], a[r][2k2+1], a[r+1][2k2], a[r+1][2k2+1]}
        // B = {b[c][2k2], b[c][2k2+1], b[c+1][2k2], b[c+1][2k2+1]}
        acc00 = fmaf(A.x, B.x, acc00); acc00 = fmaf(A.y, B.y, acc00);
        acc01 = fmaf(A.x, B.z, acc01); acc01 = fmaf(A.y, B.w, acc01);
        acc10 = fmaf(A.z, B.x, acc10); acc10 = fmaf(A.w, B.y, acc10);
        acc11 = fmaf(A.z, B.z, acc11); acc11 = fmaf(A.w, B.w, acc11);
    }

    const unsigned short u00 = __half_as_ushort(__float2half_rn(acc00));
    const unsigned short u01 = __half_as_ushort(__float2half_rn(acc01));
    const unsigned short u10 = __half_as_ushort(__float2half_rn(acc10));
    const unsigned short u11 = __half_as_ushort(__float2half_rn(acc11));

    store_bits(out + ((size_t)r       * COLS + c    ) * 16, u00);
    store_bits(out + ((size_t)r       * COLS + c + 1) * 16, u01);
    store_bits(out + ((size_t)(r + 1) * COLS + c    ) * 16, u10);
    store_bits(out + ((size_t)(r + 1) * COLS + c + 1) * 16, u11);
}

extern "C" void kernel_launch(void* const* d_in, const int* in_sizes, int n_in,
                              void* d_out, int out_size, void* d_ws, size_t ws_size,
                              hipStream_t stream) {
    const float* xp = (const float*)d_in[0];   // [ROWS][K][16] bits
    const float* wp = (const float*)d_in[1];   // [COLS][K][16] bits
    float* outp = (float*)d_out;               // [ROWS][COLS][16] bits
    float* dec  = (float*)d_ws;                // NX + NW floats (3 MB)

    const int n_elem = NX + NW;                // 786432 -> 3072 blocks
    decode_k<<<n_elem / 256, 256, 0, stream>>>(xp, wp, dec);

    dim3 grid(COLS / 32, ROWS / 32);           // (16, 32) = 512 blocks
    gemm_k<<<grid, 256, 0, stream>>>(dec, outp);
}

// Round 9
// 138.477 us; speedup vs baseline: 1.0251x; 1.0251x over previous
//
#include <hip/hip_runtime.h>
#include <hip/hip_fp16.h>

// Problem geometry (fixed by the reference)
constexpr int K    = 512;     // inner dim
constexpr int ROWS = 1024;    // B*T = 4*256
constexpr int COLS = 512;     // OUT
constexpr int NX   = ROWS * K;   // decoded x element count
constexpr int NW   = COLS * K;   // decoded w element count

// ---------------------------------------------------------------------------
// Kernel 1 (VERBATIM from the passing R1/R2 rounds): decode pulse bits ->
// exact fp16 value stored as fp32, linear layout.
// ws layout: [0, NX) = x values ([row][k]); [NX, NX+NW) = w values ([col][k]).
// ---------------------------------------------------------------------------
__global__ __launch_bounds__(256) void decode_k(const float* __restrict__ xp,
                                                const float* __restrict__ wp,
                                                float* __restrict__ dec) {
    __shared__ float lds[256 * 17];          // odd element stride: conflict-free
    const int t = threadIdx.x;
    const int ebase = blockIdx.x << 8;       // 256 elements per block
    const float4* s4 = (ebase < NX)
        ? (const float4*)(xp + (size_t)ebase * 16)
        : (const float4*)(wp + (size_t)(ebase - NX) * 16);

    #pragma unroll
    for (int j = 0; j < 4; ++j) {
        const int f = t + (j << 8);          // float4 index: 16 B lane stride
        const float4 v = s4[f];
        const int e = f >> 2;
        const int q = f & 3;
        *(float4*)&lds[e * 17 + (q << 2)] = v;
    }
    __syncthreads();

    const float* m = &lds[t * 17];
    unsigned u = 0;
    #pragma unroll
    for (int k = 0; k < 16; ++k)
        u |= ((__float_as_uint(m[k]) >> 23) & 1u) << k;   // 1.0f bit23
    dec[ebase + t] = __half2float(__ushort_as_half((unsigned short)u));
}

// ---------------------------------------------------------------------------
// Kernel 2: GEMM, bit-exact sequential fp32 accumulation (ascending k),
// then fp16 RNE + pulse re-encode.  R2's proven skeleton (LDS-staged B,
// reg-prefetch, 2 barriers/step, 4 rows x 64 cols per wave) with ONE change:
// the four A row pointers are forced into VGPRs via an empty asm so the
// compiler cannot scalarize them to s_load.  A-loads then issue as
// global_load_dwordx4 (vmcnt, same-address broadcast) and never force
// lgkmcnt(0) drains of the in-order ds_read stream -- R2's measured poison.
// ---------------------------------------------------------------------------
__global__ __launch_bounds__(256) void gemm_k(const float* __restrict__ dec,
                                              float* __restrict__ out) {
    const float* __restrict__ xv = dec;        // [ROWS][K]
    const float* __restrict__ wv = dec + NX;   // [COLS][K]

    __shared__ float Bs[64][68];               // 68-stride: benign on b128

    const int tid  = threadIdx.x;
    const int lane = tid & 63;
    const int wid  = __builtin_amdgcn_readfirstlane(tid >> 6);   // 0..3
    const int col0 = blockIdx.x << 6;          // gridDim.x = 8
    const int row0 = (blockIdx.y << 4) + (wid << 2);  // gridDim.y = 64; 4 rows/wave

    float acc[4] = {0.f, 0.f, 0.f, 0.f};

    // B staging map: 4 threads per column, 16 k's each (4 float4 loads)
    const int scol = tid >> 2;                 // 0..63
    const int skq  = (tid & 3) << 4;           // 0,16,32,48
    const float* wsrc = wv + (size_t)(col0 + scol) * K + skq;

    // prefetch first B tile into registers
    float4 t0 = *(const float4*)(wsrc + 0);
    float4 t1 = *(const float4*)(wsrc + 4);
    float4 t2 = *(const float4*)(wsrc + 8);
    float4 t3 = *(const float4*)(wsrc + 12);

    // A row pointers, devectorized: opaque asm forces VGPR residency so the
    // loads stay on the VMEM path (vmcnt).  All lanes hold the same value ->
    // HW coalesces each load to one L1 transaction + broadcast.
    const float* ar0 = xv + (size_t)(row0 + 0) * K;
    const float* ar1 = xv + (size_t)(row0 + 1) * K;
    const float* ar2 = xv + (size_t)(row0 + 2) * K;
    const float* ar3 = xv + (size_t)(row0 + 3) * K;
    asm("" : "+v"(ar0));
    asm("" : "+v"(ar1));
    asm("" : "+v"(ar2));
    asm("" : "+v"(ar3));

    for (int k0 = 0; k0 < K; k0 += 64) {
        __syncthreads();                       // previous tile fully consumed
        *(float4*)&Bs[scol][skq + 0]  = t0;
        *(float4*)&Bs[scol][skq + 4]  = t1;
        *(float4*)&Bs[scol][skq + 8]  = t2;
        *(float4*)&Bs[scol][skq + 12] = t3;
        __syncthreads();

        if (k0 + 64 < K) {                     // prefetch next tile (overlaps compute)
            t0 = *(const float4*)(wsrc + k0 + 64 + 0);
            t1 = *(const float4*)(wsrc + k0 + 64 + 4);
            t2 = *(const float4*)(wsrc + k0 + 64 + 8);
            t3 = *(const float4*)(wsrc + k0 + 64 + 12);
        }

        // Interleaved {vmcnt A-broadcast loads, lgkmcnt B ds_reads, FMA};
        // strictly ascending k per accumulator -> bit-exact.
        #pragma unroll
        for (int kc = 0; kc < 64; kc += 4) {
            const float4 b  = *(const float4*)&Bs[lane][kc];
            const float4 a0 = *(const float4*)(ar0 + k0 + kc);
            const float4 a1 = *(const float4*)(ar1 + k0 + kc);
            const float4 a2 = *(const float4*)(ar2 + k0 + kc);
            const float4 a3 = *(const float4*)(ar3 + k0 + kc);
            acc[0] = fmaf(a0.x, b.x, acc[0]); acc[0] = fmaf(a0.y, b.y, acc[0]);
            acc[0] = fmaf(a0.z, b.z, acc[0]); acc[0] = fmaf(a0.w, b.w, acc[0]);
            acc[1] = fmaf(a1.x, b.x, acc[1]); acc[1] = fmaf(a1.y, b.y, acc[1]);
            acc[1] = fmaf(a1.z, b.z, acc[1]); acc[1] = fmaf(a1.w, b.w, acc[1]);
            acc[2] = fmaf(a2.x, b.x, acc[2]); acc[2] = fmaf(a2.y, b.y, acc[2]);
            acc[2] = fmaf(a2.z, b.z, acc[2]); acc[2] = fmaf(a2.w, b.w, acc[2]);
            acc[3] = fmaf(a3.x, b.x, acc[3]); acc[3] = fmaf(a3.y, b.y, acc[3]);
            acc[3] = fmaf(a3.z, b.z, acc[3]); acc[3] = fmaf(a3.w, b.w, acc[3]);
        }
    }

    // Epilogue: fp32 -> fp16 (RNE) -> 16 pulse bits. Lane-contiguous 64 B stores.
    #pragma unroll
    for (int r = 0; r < 4; ++r) {
        const unsigned short u = __half_as_ushort(__float2half_rn(acc[r]));
        float* o = out + ((size_t)(row0 + r) * COLS + (col0 + lane)) * 16;
        float4 q;
        q.x = (float)((u >> 0) & 1);
        q.y = (float)((u >> 1) & 1);
        q.z = (float)((u >> 2) & 1);
        q.w = (float)((u >> 3) & 1);
        *(float4*)(o + 0) = q;
        q.x = (float)((u >> 4) & 1);
        q.y = (float)((u >> 5) & 1);
        q.z = (float)((u >> 6) & 1);
        q.w = (float)((u >> 7) & 1);
        *(float4*)(o + 4) = q;
        q.x = (float)((u >> 8) & 1);
        q.y = (float)((u >> 9) & 1);
        q.z = (float)((u >> 10) & 1);
        q.w = (float)((u >> 11) & 1);
        *(float4*)(o + 8) = q;
        q.x = (float)((u >> 12) & 1);
        q.y = (float)((u >> 13) & 1);
        q.z = (float)((u >> 14) & 1);
        q.w = (float)((u >> 15) & 1);
        *(float4*)(o + 12) = q;
    }
}

extern "C" void kernel_launch(void* const* d_in, const int* in_sizes, int n_in,
                              void* d_out, int out_size, void* d_ws, size_t ws_size,
                              hipStream_t stream) {
    const float* xp = (const float*)d_in[0];   // [ROWS][K][16] bits
    const float* wp = (const float*)d_in[1];   // [COLS][K][16] bits
    float* outp = (float*)d_out;               // [ROWS][COLS][16] bits
    float* dec  = (float*)d_ws;                // NX + NW floats (3 MB)

    const int n_elem = NX + NW;                // 786432 -> 3072 blocks
    decode_k<<<n_elem / 256, 256, 0, stream>>>(xp, wp, dec);

    dim3 grid(COLS / 64, ROWS / 16);           // (8, 64) = 512 blocks
    gemm_k<<<grid, 256, 0, stream>>>(dec, outp);
}